// Round 7
// baseline (192.087 us; speedup 1.0000x reference)
//
#include <hip/hip_runtime.h>
#include <math.h>

// B=32 graphs, N=1024 nodes, D=128 in-dim, C=64 out-dim, K=16.
#define OUT_ELEMS 2097152   // 32768*64
#define EDGE_ELEMS 524288   // 32*1024*16

__device__ __forceinline__ unsigned int rotl32(unsigned int x, int r){
  return (x << r) | (x >> (32 - r));
}

// JAX partitionable threefry, key (0,1): counter = (0, e); out = o0 ^ o1.
__device__ __forceinline__ unsigned int tf_bits_part(unsigned int e){
  unsigned int x0 = 0u, x1 = e;
  const unsigned int ks1 = 1u;
  const unsigned int ks2 = 0x1BD11BDBu;
  x1 += ks1;
#define TFR(r) { x0 += x1; x1 = rotl32(x1, r); x1 ^= x0; }
  TFR(13) TFR(15) TFR(26) TFR(6)
  x0 += ks1; x1 += ks2 + 1u;
  TFR(17) TFR(29) TFR(16) TFR(24)
  x0 += ks2; x1 += 0u + 2u;
  TFR(13) TFR(15) TFR(26) TFR(6)
  x0 += 0u;  x1 += ks1 + 3u;
  TFR(17) TFR(29) TFR(16) TFR(24)
  x0 += ks1; x1 += ks2 + 4u;
  TFR(13) TFR(15) TFR(26) TFR(6)
  x0 += ks2; x1 += 0u + 5u;
#undef TFR
  return x0 ^ x1;
}

// hardware f64 reciprocal + 2 Newton steps: rel err ~1e-16.
__device__ __forceinline__ double rcp64(double x){
  double r;
  asm("v_rcp_f64 %0, %1" : "=v"(r) : "v"(x));
  double e = fma(-x, r, 1.0); r = fma(r, e, r);
  e = fma(-x, r, 1.0); r = fma(r, e, r);
  return r;
}

// fast e^x for x in [-740, ~1]; rel err ~2e-11 (deg-9).
__device__ __forceinline__ double fast_exp(double x){
  double fn = __builtin_rint(x * 1.4426950408889634);
  int n = (int)fn;
  double r = fma(fn, -0.6931471803691238, x);
  r = fma(fn, -1.9082149292705877e-10, r);
  double p = 2.7557319223985893e-06;
  p = fma(r, p, 2.4801587301587302e-05);
  p = fma(r, p, 1.9841269841269841e-04);
  p = fma(r, p, 1.3888888888888889e-03);
  p = fma(r, p, 8.3333333333333333e-03);
  p = fma(r, p, 4.1666666666666664e-02);
  p = fma(r, p, 1.6666666666666666e-01);
  p = fma(r, p, 0.5);
  p = fma(r, p, 1.0);
  p = fma(r, p, 1.0);
  double scale = __longlong_as_double(((long long)(n + 1023)) << 52);
  return p * scale;
}

// fast ln(x), normal positive x; atanh form; abs err ~2e-11.
__device__ __forceinline__ double fast_log(double x){
  long long bx = __double_as_longlong(x);
  long long e = (bx >> 52) - 1023;
  double m = __longlong_as_double((bx & 0xFFFFFFFFFFFFFll) |
                                  0x3FF0000000000000ll);
  int big = m > 1.4142135623730951;
  m = big ? 0.5 * m : m;
  e += big;
  double s = (m - 1.0) * rcp64(m + 1.0);
  double s2 = s * s;
  double p = fma(s2, 2.0/11.0, 2.0/9.0);
  p = fma(s2, p, 2.0/7.0);
  p = fma(s2, p, 2.0/5.0);
  p = fma(s2, p, 2.0/3.0);
  double lm = fma(s * s2, p, 2.0 * s);
  return fma((double)e, 0.6931471805599453, lm);
}

// f32 squared distance; arithmetic identical to v16's score head.
__device__ __forceinline__ float dist2_f32(
    const float* __restrict__ og, const float* __restrict__ hrowf,
    unsigned int jc){
  const float4* cp4 = (const float4*)(og + ((size_t)jc << 6));
  const float4* hp4 = (const float4*)hrowf;
  float a0 = 0.0f, a1 = 0.0f, a2 = 0.0f, a3 = 0.0f;
  #pragma unroll 4
  for (int ch = 0; ch < 16; ++ch){
    float4 cf = cp4[ch];
    float4 hf = hp4[ch];
    float d0 = hf.x - cf.x;
    float d1 = hf.y - cf.y;
    float d2 = hf.z - cf.z;
    float d3 = hf.w - cf.w;
    a0 = fmaf(d0, d0, a0);
    a1 = fmaf(d1, d1, a1);
    a2 = fmaf(d2, d2, a2);
    a3 = fmaf(d3, d3, a3);
  }
  return (a0 + a1) + (a2 + a3);
}

// order-preserving u64 pack, low 10 bits = inverted index (v16 identical).
__device__ __forceinline__ unsigned long long pack_key(double sc,
                                                       unsigned int jc){
  unsigned long long kb = (unsigned long long)__double_as_longlong(sc);
  kb ^= (unsigned long long)(((long long)kb) >> 63) | 0x8000000000000000ull;
  return (kb & ~1023ull) | (unsigned long long)(1023u - jc);
}

// exact f64 tail — bit-identical keys to v16 (bits come from phase-1 store).
__device__ __forceinline__ unsigned long long tail64(
    float accf, unsigned int bits, unsigned int jc, double Td, bool act){
  if (!act) return 0ull;
  double sgm = fast_exp(-Td * (double)accf);
  float f = __uint_as_float(0x3f800000u | (bits >> 9)) - 1.0f;
  double u = (f > 0.0f) ? (double)f : 1.1754943508222875e-38;
  double w = -fast_log(u);
  double z = -fast_log(w);
  double sc = sgm + z;
  return pack_key(sc, jc);
}

// fast f32 tail; |score - tail64 score| <= ~3e-6 (2-ulp HW exp/log bound).
__device__ __forceinline__ unsigned long long tail32(
    float accf, unsigned int bits, unsigned int jc, float Tf, bool act){
  if (!act) return 0ull;
  float sg = __expf(-Tf * accf);
  float f = __uint_as_float(0x3f800000u | (bits >> 9)) - 1.0f;
  float uf = (f > 0.0f) ? f : 1.17549435e-38f;   // FLT_MIN (normal)
  float wv = -__logf(uf);
  float zf = -__logf(wv);
  double sc = (double)sg + (double)zf;
  return pack_key(sc, jc);
}

// inverse of pack_key's order map (low 10 index bits zeroed: ~2e-13 rel).
__device__ __forceinline__ double key_score(unsigned long long k){
  unsigned long long orig = (k >> 63) ? (k ^ 0x8000000000000000ull) : ~k;
  return __longlong_as_double((long long)(orig & ~1023ull));
}

// Full descending bitonic sort of u64 keys across 64 lanes.
__device__ __forceinline__ unsigned long long bitonic64_desc(
    unsigned long long key, int lane){
  #pragma unroll
  for (int k = 2; k <= 64; k <<= 1){
    #pragma unroll
    for (int j = k >> 1; j; j >>= 1){
      unsigned long long o = __shfl_xor(key, j, 64);
      bool keep_hi = ((lane & k) == 0) == ((lane & j) == 0);
      key = (keep_hi == (o > key)) ? o : key;
    }
  }
  return key;
}

// Full descending bitonic sort of u32 keys across 64 lanes.
__device__ __forceinline__ unsigned int bitonic32_desc(
    unsigned int key, int lane){
  #pragma unroll
  for (int k = 2; k <= 64; k <<= 1){
    #pragma unroll
    for (int j = k >> 1; j; j >>= 1){
      unsigned int o = __shfl_xor(key, j, 64);
      bool keep_hi = ((lane & k) == 0) == ((lane & j) == 0);
      key = (keep_hi == (o > key)) ? o : key;
    }
  }
  return key;
}

// ---------------- prekernel: W,b -> f64 in workspace ----------------
__global__ __launch_bounds__(256) void cvt_wb_v17(
    const float* __restrict__ W, const float* __restrict__ b,
    double* __restrict__ w64, double* __restrict__ b64){
  const int i = blockIdx.x * 256 + threadIdx.x;
  if (i < 8192)      w64[i] = (double)W[i];
  else if (i < 8256) b64[i - 8192] = (double)b[i - 8192];
}

// ---------------- encoder ----------------
// Exact v15/v16 encoder (proven: out BIT-IDENTICAL, absmax 480.0).
// lane = row; W via uniform s_load from pre-cvt'd f64; x tile in padded LDS.
__global__ __launch_bounds__(512) void encoder_v17(
    const float* __restrict__ x, const double* __restrict__ w64,
    const double* __restrict__ b64, float* __restrict__ out){
  __shared__ float xs[64 * 129];        // 33 KB, +1-dword pad per row
  const int tid = threadIdx.x;

  { // stage 64x128 x tile, coalesced float4 loads, padded scatter
    const float4* xg4 = (const float4*)(x + ((size_t)blockIdx.x << 13));
    #pragma unroll
    for (int s = 0; s < 4; ++s){
      const int idx = tid + (s << 9);   // 0..2047 float4s
      float4 v = xg4[idx];
      const int r = idx >> 5, k4 = (idx & 31) << 2;
      float* p = &xs[r * 129 + k4];
      p[0] = v.x; p[1] = v.y; p[2] = v.z; p[3] = v.w;
    }
  }
  __syncthreads();

  const int lane = tid & 63;                                  // row
  const int wu = __builtin_amdgcn_readfirstlane(tid >> 6);    // wave (SGPR)
  const int c0 = wu << 3;                                     // 8 cols/wave
  const size_t row = ((size_t)blockIdx.x << 6) + (size_t)lane;

  double acc[8];
  const double* __restrict__ bp = b64 + c0;   // uniform -> s_load
  #pragma unroll
  for (int j = 0; j < 8; ++j) acc[j] = bp[j];

  const float* __restrict__ xrow = &xs[lane * 129];
  #pragma unroll 4
  for (int k = 0; k < 128; ++k){
    const double xk = (double)xrow[k];                 // ds_read + 1 cvt
    const double* __restrict__ wp = w64 + (k << 6) + c0;  // uniform -> s_load
    #pragma unroll
    for (int j = 0; j < 8; ++j)
      acc[j] = fma(xk, wp[j], acc[j]);
  }

  float* __restrict__ orow = out + (row << 6) + c0;
  #pragma unroll
  for (int j2 = 0; j2 < 4; ++j2){
    float2 st; st.x = (float)acc[(j2 << 1)]; st.y = (float)acc[(j2 << 1) + 1];
    *(float2*)&orow[j2 << 1] = st;
  }
}

// ---------------- edges ----------------
// v17: phases 1-3 store FULL threefry bits with each surviving candidate
// (cl64 = bits<<32 | j) -> phase 4 never recomputes threefry (exact).
// Phase-4 tail runs in f32 (HW __expf/__logf, ~40 cyc vs ~800 for the f64
// polys); after the sort, any adjacent top-16 score gap < 4e-5 (13x the
// 3e-6 f32-tail error bound) triggers a per-wave EXACT f64 redo using the
// cached distances + stored bits -> keys bit-identical to v16 whenever the
// fast path could possibly disagree. nc>64 rows (P~1e-3) go straight to
// the exact two-chunk f64 path.
__global__ __launch_bounds__(256, 8) void edges_v17(
    const float* __restrict__ out32, const float* __restrict__ temp,
    float* __restrict__ rows_out, float* __restrict__ cols_out){
  __shared__ float hidf[4][64];                 // 1 KB
  __shared__ unsigned long long cl64[4][128];   // 4 KB
  const int tid = threadIdx.x, wave = tid >> 6, lane = tid & 63;
  const int gb = blockIdx.x >> 8;
  const int i0 = (blockIdx.x & 255) << 2;
  const int r  = i0 + wave;
  const float* __restrict__ og = out32 + ((size_t)gb << 16);

  hidf[wave][lane] = og[((size_t)r << 6) + lane];

  const unsigned int base = ((unsigned int)gb << 20) | ((unsigned int)r << 10);

  // Phase 1: full bits for j = m*64 + lane, running per-lane max of v(m)
  unsigned int b[16];
  unsigned int pmax = 0u;
  #pragma unroll
  for (int m = 0; m < 16; ++m){
    const unsigned int j = (unsigned int)(m << 6) + (unsigned int)lane;
    b[m] = tf_bits_part(base | j);
    const unsigned int vm = (b[m] & ~1023u) | (1023u - j);
    pmax = (vm > pmax) ? vm : pmax;
  }

  // Phase 2: 16th-largest lane-max (conservative surrogate for b16)
  unsigned int sorted = bitonic32_desc(pmax, lane);
  unsigned int b16p = __shfl(sorted, 15, 64);

  // conservative cut: keep j iff z_j >= z(b16') - 1.001  (score <= z + 1)
  float u16 = __uint_as_float(0x3f800000u | (b16p >> 9)) - 1.0f;
  float z16 = -__logf(-__logf(u16));
  float uc  = __expf(-__expf(-(z16 - 1.001f)));
  unsigned int cp = ((__float_as_uint(1.0f + uc) & 0x7FFFFFu) << 9) & ~1023u;

  // Phase 3: compaction of all survivors (>=16 guaranteed since cut < b16')
  int cnt = 0;
  #pragma unroll
  for (int m = 0; m < 16; ++m){
    const unsigned int j = (unsigned int)(m << 6) + (unsigned int)lane;
    const unsigned int vm = (b[m] & ~1023u) | (1023u - j);
    cnt += (vm >= cp) ? 1 : 0;
  }
  int s = cnt;
  #pragma unroll
  for (int off = 1; off < 64; off <<= 1){
    int o = __shfl_up(s, off, 64);
    s += (lane >= off) ? o : 0;
  }
  int nc = __shfl(s, 63, 64);
  nc = (nc > 128) ? 128 : nc;
  int slot = s - cnt;
  #pragma unroll
  for (int m = 0; m < 16; ++m){
    const unsigned int j = (unsigned int)(m << 6) + (unsigned int)lane;
    const unsigned int vm = (b[m] & ~1023u) | (1023u - j);
    if (vm >= cp && slot < 128){
      cl64[wave][slot] = ((unsigned long long)b[m] << 32) |
                         (unsigned long long)j;
      ++slot;
    }
  }

  // Phase 4: scoring + top-16
  const double Td = (double)temp[0];
  const float  Tf = temp[0];
  unsigned long long key;

  if (nc <= 64){
    const bool act1 = (lane < nc);
    const unsigned long long e1 = act1 ? cl64[wave][lane] : 0ull;
    const unsigned int jc1 = (unsigned int)(e1 & 1023ull);
    const unsigned int bt1 = (unsigned int)(e1 >> 32);
    const float ac1 = dist2_f32(og, &hidf[wave][0], jc1);
    key = tail32(ac1, bt1, jc1, Tf, act1);
    key = bitonic64_desc(key, lane);
    // guard: adjacent top-16 gap below threshold -> exact f64 redo
    double s0 = key_score(key);
    unsigned long long kn = __shfl_down(key, 1, 64);
    double s1 = key_score(kn);
    bool tight = (lane < 16) && (key != 0ull) && ((s0 - s1) < 4e-5);
    if (__any(tight)){
      key = tail64(ac1, bt1, jc1, Td, act1);
      key = bitonic64_desc(key, lane);
    }
  } else {
    // rare two-chunk exact path (v16 semantics, bits from LDS)
    const bool act1 = (lane < nc);
    const unsigned long long e1 = act1 ? cl64[wave][lane] : 0ull;
    const unsigned int jc1 = (unsigned int)(e1 & 1023ull);
    const unsigned int bt1 = (unsigned int)(e1 >> 32);
    const float ac1 = dist2_f32(og, &hidf[wave][0], jc1);
    key = tail64(ac1, bt1, jc1, Td, act1);
    key = bitonic64_desc(key, lane);

    const int idx2 = 64 + lane;
    const bool act2 = (idx2 < nc);
    const unsigned long long e2 = act2 ? cl64[wave][idx2] : 0ull;
    const unsigned int jc2 = (unsigned int)(e2 & 1023ull);
    const unsigned int bt2 = (unsigned int)(e2 >> 32);
    const float ac2 = dist2_f32(og, &hidf[wave][0], jc2);
    unsigned long long k2 = tail64(ac2, bt2, jc2, Td, act2);
    k2 = bitonic64_desc(k2, lane);
    unsigned long long kr = __shfl(k2, 63 - lane, 64);
    key = (kr > key) ? kr : key;          // elementwise top-64 (bitonic)
    #pragma unroll
    for (int j2 = 32; j2; j2 >>= 1){      // descending clean
      unsigned long long o = __shfl_xor(key, j2, 64);
      bool left = (lane & j2) == 0;
      bool take = left ? (o > key) : (o < key);
      key = take ? o : key;
    }
  }

  const int grow = (gb << 10) + r;
  if (lane < 16){
    rows_out[((size_t)grow << 4) + lane] = (float)grow;
    cols_out[((size_t)grow << 4) + lane] =
        (float)((gb << 10) + (1023 - (int)(key & 1023ull)));
  }
}

extern "C" void kernel_launch(void* const* d_in, const int* in_sizes, int n_in,
                              void* d_out, int out_size, void* d_ws, size_t ws_size,
                              hipStream_t stream){
  const float* x = (const float*)d_in[0];
  const float* W = (const float*)d_in[1];
  const float* b = (const float*)d_in[2];
  const float* T = (const float*)d_in[3];
  float* out      = (float*)d_out;
  float* rows_out = out + OUT_ELEMS;
  float* cols_out = rows_out + EDGE_ELEMS;

  double* w64 = (double*)d_ws;           // 8192 f64 = 64 KB
  double* b64 = w64 + 8192;              // 64 f64

  cvt_wb_v17<<<33, 256, 0, stream>>>(W, b, w64, b64);
  encoder_v17<<<512, 512, 0, stream>>>(x, w64, b64, out);
  edges_v17<<<8192, 256, 0, stream>>>(out, T, rows_out, cols_out);
}

// Round 8
// 177.050 us; speedup vs baseline: 1.0849x; 1.0849x over previous
//
#include <hip/hip_runtime.h>
#include <math.h>

// B=32 graphs, N=1024 nodes, D=128 in-dim, C=64 out-dim, K=16.
#define OUT_ELEMS 2097152   // 32768*64
#define EDGE_ELEMS 524288   // 32*1024*16

__device__ __forceinline__ unsigned int rotl32(unsigned int x, int r){
  return (x << r) | (x >> (32 - r));
}

// JAX partitionable threefry, key (0,1): counter = (0, e); out = o0 ^ o1.
__device__ __forceinline__ unsigned int tf_bits_part(unsigned int e){
  unsigned int x0 = 0u, x1 = e;
  const unsigned int ks1 = 1u;
  const unsigned int ks2 = 0x1BD11BDBu;
  x1 += ks1;
#define TFR(r) { x0 += x1; x1 = rotl32(x1, r); x1 ^= x0; }
  TFR(13) TFR(15) TFR(26) TFR(6)
  x0 += ks1; x1 += ks2 + 1u;
  TFR(17) TFR(29) TFR(16) TFR(24)
  x0 += ks2; x1 += 0u + 2u;
  TFR(13) TFR(15) TFR(26) TFR(6)
  x0 += 0u;  x1 += ks1 + 3u;
  TFR(17) TFR(29) TFR(16) TFR(24)
  x0 += ks1; x1 += ks2 + 4u;
  TFR(13) TFR(15) TFR(26) TFR(6)
  x0 += ks2; x1 += 0u + 5u;
#undef TFR
  return x0 ^ x1;
}

// hardware f64 reciprocal + 2 Newton steps: rel err ~1e-16.
__device__ __forceinline__ double rcp64(double x){
  double r;
  asm("v_rcp_f64 %0, %1" : "=v"(r) : "v"(x));
  double e = fma(-x, r, 1.0); r = fma(r, e, r);
  e = fma(-x, r, 1.0); r = fma(r, e, r);
  return r;
}

// fast e^x for x in [-740, ~1]; rel err ~2e-11 (deg-9).
__device__ __forceinline__ double fast_exp(double x){
  double fn = __builtin_rint(x * 1.4426950408889634);
  int n = (int)fn;
  double r = fma(fn, -0.6931471803691238, x);
  r = fma(fn, -1.9082149292705877e-10, r);
  double p = 2.7557319223985893e-06;
  p = fma(r, p, 2.4801587301587302e-05);
  p = fma(r, p, 1.9841269841269841e-04);
  p = fma(r, p, 1.3888888888888889e-03);
  p = fma(r, p, 8.3333333333333333e-03);
  p = fma(r, p, 4.1666666666666664e-02);
  p = fma(r, p, 1.6666666666666666e-01);
  p = fma(r, p, 0.5);
  p = fma(r, p, 1.0);
  p = fma(r, p, 1.0);
  double scale = __longlong_as_double(((long long)(n + 1023)) << 52);
  return p * scale;
}

// fast ln(x), normal positive x; atanh form; abs err ~2e-11.
__device__ __forceinline__ double fast_log(double x){
  long long bx = __double_as_longlong(x);
  long long e = (bx >> 52) - 1023;
  double m = __longlong_as_double((bx & 0xFFFFFFFFFFFFFll) |
                                  0x3FF0000000000000ll);
  int big = m > 1.4142135623730951;
  m = big ? 0.5 * m : m;
  e += big;
  double s = (m - 1.0) * rcp64(m + 1.0);
  double s2 = s * s;
  double p = fma(s2, 2.0/11.0, 2.0/9.0);
  p = fma(s2, p, 2.0/7.0);
  p = fma(s2, p, 2.0/5.0);
  p = fma(s2, p, 2.0/3.0);
  double lm = fma(s * s2, p, 2.0 * s);
  return fma((double)e, 0.6931471805599453, lm);
}

// f32 squared distance; arithmetic identical to v16's score head.
__device__ __forceinline__ float dist2_f32(
    const float* __restrict__ og, const float* __restrict__ hrowf,
    unsigned int jc){
  const float4* cp4 = (const float4*)(og + ((size_t)jc << 6));
  const float4* hp4 = (const float4*)hrowf;
  float a0 = 0.0f, a1 = 0.0f, a2 = 0.0f, a3 = 0.0f;
  #pragma unroll 4
  for (int ch = 0; ch < 16; ++ch){
    float4 cf = cp4[ch];
    float4 hf = hp4[ch];
    float d0 = hf.x - cf.x;
    float d1 = hf.y - cf.y;
    float d2 = hf.z - cf.z;
    float d3 = hf.w - cf.w;
    a0 = fmaf(d0, d0, a0);
    a1 = fmaf(d1, d1, a1);
    a2 = fmaf(d2, d2, a2);
    a3 = fmaf(d3, d3, a3);
  }
  return (a0 + a1) + (a2 + a3);
}

// order-preserving u64 pack, low 10 bits = inverted index (v16 identical).
__device__ __forceinline__ unsigned long long pack_key(double sc,
                                                       unsigned int jc){
  unsigned long long kb = (unsigned long long)__double_as_longlong(sc);
  kb ^= (unsigned long long)(((long long)kb) >> 63) | 0x8000000000000000ull;
  return (kb & ~1023ull) | (unsigned long long)(1023u - jc);
}

// exact f64 tail — keys bit-identical to v16's score_cand32.
__device__ __forceinline__ unsigned long long tail64(
    float accf, unsigned int bits, unsigned int jc, double Td, bool act){
  if (!act) return 0ull;
  double sgm = fast_exp(-Td * (double)accf);
  float f = __uint_as_float(0x3f800000u | (bits >> 9)) - 1.0f;
  double u = (f > 0.0f) ? (double)f : 1.1754943508222875e-38;
  double w = -fast_log(u);
  double z = -fast_log(w);
  double sc = sgm + z;
  return pack_key(sc, jc);
}

// fast f32 tail; |score - tail64 score| <= ~5e-7 (HW exp/log 1-2 ulp).
__device__ __forceinline__ unsigned long long tail32(
    float accf, unsigned int bits, unsigned int jc, float Tf, bool act){
  if (!act) return 0ull;
  float sg = __expf(-Tf * accf);
  float f = __uint_as_float(0x3f800000u | (bits >> 9)) - 1.0f;
  float uf = (f > 0.0f) ? f : 1.17549435e-38f;   // FLT_MIN (normal)
  float wv = -__logf(uf);
  float zf = -__logf(wv);
  double sc = (double)sg + (double)zf;
  return pack_key(sc, jc);
}

// inverse of pack_key's order map (low 10 index bits zeroed: ~2e-13 rel).
__device__ __forceinline__ double key_score(unsigned long long k){
  unsigned long long orig = (k >> 63) ? (k ^ 0x8000000000000000ull) : ~k;
  return __longlong_as_double((long long)(orig & ~1023ull));
}

// Full descending bitonic sort of u64 keys across 64 lanes.
__device__ __forceinline__ unsigned long long bitonic64_desc(
    unsigned long long key, int lane){
  #pragma unroll
  for (int k = 2; k <= 64; k <<= 1){
    #pragma unroll
    for (int j = k >> 1; j; j >>= 1){
      unsigned long long o = __shfl_xor(key, j, 64);
      bool keep_hi = ((lane & k) == 0) == ((lane & j) == 0);
      key = (keep_hi == (o > key)) ? o : key;
    }
  }
  return key;
}

// Full descending bitonic sort of u32 keys across 64 lanes.
__device__ __forceinline__ unsigned int bitonic32_desc(
    unsigned int key, int lane){
  #pragma unroll
  for (int k = 2; k <= 64; k <<= 1){
    #pragma unroll
    for (int j = k >> 1; j; j >>= 1){
      unsigned int o = __shfl_xor(key, j, 64);
      bool keep_hi = ((lane & k) == 0) == ((lane & j) == 0);
      key = (keep_hi == (o > key)) ? o : key;
    }
  }
  return key;
}

// ---------------- prekernel: W,b -> f64 in workspace ----------------
__global__ __launch_bounds__(256) void cvt_wb_v18(
    const float* __restrict__ W, const float* __restrict__ b,
    double* __restrict__ w64, double* __restrict__ b64){
  const int i = blockIdx.x * 256 + threadIdx.x;
  if (i < 8192)      w64[i] = (double)W[i];
  else if (i < 8256) b64[i - 8192] = (double)b[i - 8192];
}

// ---------------- encoder ----------------
// Exact v15/v16 encoder (proven: out BIT-IDENTICAL, absmax 480.0).
// lane = row; W via uniform s_load from pre-cvt'd f64; x tile in padded LDS.
__global__ __launch_bounds__(512) void encoder_v18(
    const float* __restrict__ x, const double* __restrict__ w64,
    const double* __restrict__ b64, float* __restrict__ out){
  __shared__ float xs[64 * 129];        // 33 KB, +1-dword pad per row
  const int tid = threadIdx.x;

  { // stage 64x128 x tile, coalesced float4 loads, padded scatter
    const float4* xg4 = (const float4*)(x + ((size_t)blockIdx.x << 13));
    #pragma unroll
    for (int s = 0; s < 4; ++s){
      const int idx = tid + (s << 9);   // 0..2047 float4s
      float4 v = xg4[idx];
      const int r = idx >> 5, k4 = (idx & 31) << 2;
      float* p = &xs[r * 129 + k4];
      p[0] = v.x; p[1] = v.y; p[2] = v.z; p[3] = v.w;
    }
  }
  __syncthreads();

  const int lane = tid & 63;                                  // row
  const int wu = __builtin_amdgcn_readfirstlane(tid >> 6);    // wave (SGPR)
  const int c0 = wu << 3;                                     // 8 cols/wave
  const size_t row = ((size_t)blockIdx.x << 6) + (size_t)lane;

  double acc[8];
  const double* __restrict__ bp = b64 + c0;   // uniform -> s_load
  #pragma unroll
  for (int j = 0; j < 8; ++j) acc[j] = bp[j];

  const float* __restrict__ xrow = &xs[lane * 129];
  #pragma unroll 4
  for (int k = 0; k < 128; ++k){
    const double xk = (double)xrow[k];                 // ds_read + 1 cvt
    const double* __restrict__ wp = w64 + (k << 6) + c0;  // uniform -> s_load
    #pragma unroll
    for (int j = 0; j < 8; ++j)
      acc[j] = fma(xk, wp[j], acc[j]);
  }

  float* __restrict__ orow = out + (row << 6) + c0;
  #pragma unroll
  for (int j2 = 0; j2 < 4; ++j2){
    float2 st; st.x = (float)acc[(j2 << 1)]; st.y = (float)acc[(j2 << 1) + 1];
    *(float2*)&orow[j2 << 1] = st;
  }
}

// ---------------- edges ----------------
// v18 = v16's exact register structure (u32 cl, v[16], threefry recomputed in
// phase 4 — v17's bits-storage spilled to scratch: WRITE_SIZE 4->274 MB).
// Only change vs v16: the phase-4 tail runs in f32 (HW __expf/__logf, ~40 cyc
// vs ~800 for the f64 polys). Guard: after the sort, any adjacent top-16
// score gap < 4e-5 (>=80x the ~5e-7 f32-tail error bound) triggers a
// per-wave exact f64 redo using the cached distance -> keys bit-identical
// to v16 whenever the fast path could possibly disagree. nc>64 rows
// (P~1e-3) take the v16-verbatim exact path.
__global__ __launch_bounds__(256, 8) void edges_v18(
    const float* __restrict__ out32, const float* __restrict__ temp,
    float* __restrict__ rows_out, float* __restrict__ cols_out){
  __shared__ float hidf[4][64];         // 1 KB
  __shared__ unsigned int cl[4][128];   // 2 KB
  const int tid = threadIdx.x, wave = tid >> 6, lane = tid & 63;
  const int gb = blockIdx.x >> 8;
  const int i0 = (blockIdx.x & 255) << 2;
  const int r  = i0 + wave;
  const float* __restrict__ og = out32 + ((size_t)gb << 16);

  hidf[wave][lane] = og[((size_t)r << 6) + lane];

  const unsigned int base = ((unsigned int)gb << 20) | ((unsigned int)r << 10);

  // Phase 1: bits for j = m*64 + lane, with running per-lane max
  unsigned int v[16];
  unsigned int pmax = 0u;
  #pragma unroll
  for (int m = 0; m < 16; ++m){
    const unsigned int j = (unsigned int)(m << 6) + (unsigned int)lane;
    unsigned int bits = tf_bits_part(base | j);
    v[m] = (bits & ~1023u) | (1023u - j);   // low 10 bits don't feed u
    pmax = (v[m] > pmax) ? v[m] : pmax;
  }

  // Phase 2: 16th-largest lane-max (conservative surrogate for b16)
  unsigned int sorted = bitonic32_desc(pmax, lane);
  unsigned int b16p = __shfl(sorted, 15, 64);

  // conservative cut: keep j iff z_j >= z(b16') - 1.001  (score <= z + 1)
  float u16 = __uint_as_float(0x3f800000u | (b16p >> 9)) - 1.0f;
  float z16 = -__logf(-__logf(u16));
  float uc  = __expf(-__expf(-(z16 - 1.001f)));
  unsigned int cp = ((__float_as_uint(1.0f + uc) & 0x7FFFFFu) << 9) & ~1023u;

  // Phase 3: compaction of all survivors (>=16 guaranteed since cut < b16')
  int cnt = 0;
  #pragma unroll
  for (int m = 0; m < 16; ++m) cnt += (v[m] >= cp) ? 1 : 0;
  int s = cnt;
  #pragma unroll
  for (int off = 1; off < 64; off <<= 1){
    int o = __shfl_up(s, off, 64);
    s += (lane >= off) ? o : 0;
  }
  int nc = __shfl(s, 63, 64);
  nc = (nc > 128) ? 128 : nc;
  int slot = s - cnt;
  #pragma unroll
  for (int m = 0; m < 16; ++m){
    if (v[m] >= cp && slot < 128){
      cl[wave][slot] = 1023u - (v[m] & 1023u);
      ++slot;
    }
  }

  // Phase 4: scoring (f32 dist + f32 tail, guarded) + top-16
  const double Td = (double)temp[0];
  const float  Tf = temp[0];
  unsigned long long key;

  if (nc <= 64){
    const bool act1 = (lane < nc);
    const unsigned int jc1 = act1 ? cl[wave][lane] : 0u;
    const float ac1 = dist2_f32(og, &hidf[wave][0], jc1);
    const unsigned int bt1 = tf_bits_part(base | jc1);
    key = tail32(ac1, bt1, jc1, Tf, act1);
    key = bitonic64_desc(key, lane);
    // guard: adjacent top-16 gap below threshold -> exact f64 redo
    double s0 = key_score(key);
    unsigned long long kn = __shfl_down(key, 1, 64);
    double s1 = key_score(kn);
    bool tight = (lane < 16) && (key != 0ull) && ((s0 - s1) < 4e-5);
    if (__any(tight)){
      key = tail64(ac1, bt1, jc1, Td, act1);
      key = bitonic64_desc(key, lane);
    }
  } else {
    // rare two-chunk exact path (v16 verbatim semantics)
    const bool act1 = (lane < nc);
    const unsigned int jc1 = act1 ? cl[wave][lane] : 0u;
    const float ac1 = dist2_f32(og, &hidf[wave][0], jc1);
    const unsigned int bt1 = tf_bits_part(base | jc1);
    key = tail64(ac1, bt1, jc1, Td, act1);
    key = bitonic64_desc(key, lane);

    const int idx2 = 64 + lane;
    const bool act2 = (idx2 < nc);
    const unsigned int jc2 = act2 ? cl[wave][idx2] : 0u;
    const float ac2 = dist2_f32(og, &hidf[wave][0], jc2);
    const unsigned int bt2 = tf_bits_part(base | jc2);
    unsigned long long k2 = tail64(ac2, bt2, jc2, Td, act2);
    k2 = bitonic64_desc(k2, lane);
    unsigned long long kr = __shfl(k2, 63 - lane, 64);
    key = (kr > key) ? kr : key;          // elementwise top-64 (bitonic)
    #pragma unroll
    for (int j2 = 32; j2; j2 >>= 1){      // descending clean
      unsigned long long o = __shfl_xor(key, j2, 64);
      bool left = (lane & j2) == 0;
      bool take = left ? (o > key) : (o < key);
      key = take ? o : key;
    }
  }

  const int grow = (gb << 10) + r;
  if (lane < 16){
    rows_out[((size_t)grow << 4) + lane] = (float)grow;
    cols_out[((size_t)grow << 4) + lane] =
        (float)((gb << 10) + (1023 - (int)(key & 1023ull)));
  }
}

extern "C" void kernel_launch(void* const* d_in, const int* in_sizes, int n_in,
                              void* d_out, int out_size, void* d_ws, size_t ws_size,
                              hipStream_t stream){
  const float* x = (const float*)d_in[0];
  const float* W = (const float*)d_in[1];
  const float* b = (const float*)d_in[2];
  const float* T = (const float*)d_in[3];
  float* out      = (float*)d_out;
  float* rows_out = out + OUT_ELEMS;
  float* cols_out = rows_out + EDGE_ELEMS;

  double* w64 = (double*)d_ws;           // 8192 f64 = 64 KB
  double* b64 = w64 + 8192;              // 64 f64

  cvt_wb_v18<<<33, 256, 0, stream>>>(W, b, w64, b64);
  encoder_v18<<<512, 512, 0, stream>>>(x, w64, b64, out);
  edges_v18<<<8192, 256, 0, stream>>>(out, T, rows_out, cols_out);
}